// Round 10
// baseline (1035.370 us; speedup 1.0000x reference)
//
#include <hip/hip_runtime.h>
#include <math.h>
#include <float.h>

#define BNS_C 0.9999950000374996f /* 1/sqrt(1+1e-5) */

typedef __bf16 bf8 __attribute__((ext_vector_type(8)));
typedef float f4 __attribute__((ext_vector_type(4)));
union I4BF8 { int4 i; bf8 b; };

static __device__ __forceinline__ unsigned short f2bf(float f) {
    unsigned u = __float_as_uint(f);
    u += 0x7fff + ((u >> 16) & 1);          // round-to-nearest-even
    return (unsigned short)(u >> 16);
}

// ------- x[b][6][1024] -> X0[b][n][8] (zero-padded) + xx norms -------
__global__ void k_xin_t(const float* __restrict__ x, float* __restrict__ X0, float* __restrict__ xx) {
    int i = blockIdx.x * 256 + threadIdx.x;   // over 16384 points
    int b = i >> 10, n = i & 1023;
    const float* xb = x + (((size_t)b * 6) << 10) + n;
    float4* o4 = (float4*)(X0 + ((size_t)i << 3));
    float v0 = xb[0], v1 = xb[1 << 10], v2 = xb[2 << 10];
    float v3 = xb[3 << 10], v4 = xb[4 << 10], v5 = xb[5 << 10];
    o4[0] = make_float4(v0, v1, v2, v3);
    o4[1] = make_float4(v4, v5, 0.f, 0.f);
    xx[i] = v0*v0 + v1*v1 + v2*v2 + v3*v3 + v4*v4 + v5*v5;
}

// ---- D[z][n][m] = 2*X[n]·X[m] - xx[n] - xx[m], X point-major; z over chunk ----
__global__ __launch_bounds__(256) void k_gram2(const float* __restrict__ X, const float* __restrict__ xx,
                                               float* __restrict__ D, int Cp, int b0) {
    int z = blockIdx.z, b = b0 + z;
    int n0 = blockIdx.y * 64, m0 = blockIdx.x * 64;
    __shared__ float As[64][33], Bs[64][33];
    int tid = threadIdx.x;
    int ti = tid & 15, tj = tid >> 4;
    float acc[4][4] = {};
    const float* Xb = X + (((size_t)b) << 10) * Cp;
    for (int c0 = 0; c0 < Cp; c0 += 32) {
        for (int e = tid; e < 2048; e += 256) {
            int row = e >> 5, cc = e & 31, c = c0 + cc;
            float a = 0.f, bb = 0.f;
            if (c < Cp) {
                a  = Xb[(size_t)(n0 + row) * Cp + c];
                bb = Xb[(size_t)(m0 + row) * Cp + c];
            }
            As[row][cc] = a; Bs[row][cc] = bb;
        }
        __syncthreads();
#pragma unroll 8
        for (int cc = 0; cc < 32; ++cc) {
            float xv[4], yv[4];
#pragma unroll
            for (int a = 0; a < 4; ++a) xv[a] = As[tj + 16 * a][cc];
#pragma unroll
            for (int q = 0; q < 4; ++q) yv[q] = Bs[ti + 16 * q][cc];
#pragma unroll
            for (int a = 0; a < 4; ++a)
#pragma unroll
                for (int q = 0; q < 4; ++q) acc[a][q] += xv[a] * yv[q];
        }
        __syncthreads();
    }
#pragma unroll
    for (int a = 0; a < 4; ++a) {
        int n = n0 + tj + 16 * a;
        float xn = xx[(b << 10) + n];
#pragma unroll
        for (int q = 0; q < 4; ++q) {
            int m = m0 + ti + 16 * q;
            D[((size_t)((z << 10) + n) << 10) + m] = 2.f * acc[a][q] - xn - xx[(b << 10) + m];
        }
    }
}

// ---------------- top-20 per row, one wave per row (rows chunk-local) ----------------
__global__ __launch_bounds__(256) void k_topk(const float* __restrict__ D, int* __restrict__ idxo, int b0) {
    const int K = 20;
    int lane = threadIdx.x & 63;
    int rl = blockIdx.x * 4 + (threadIdx.x >> 6);
    const float* row = D + ((size_t)rl << 10);
    float d[16];
#pragma unroll
    for (int j = 0; j < 16; ++j) d[j] = row[lane + 64 * j];
    int rg = (b0 << 10) + rl;
    for (int it = 0; it < K; ++it) {
        float bv = d[0]; int bj = 0;
#pragma unroll
        for (int j = 1; j < 16; ++j) if (d[j] > bv) { bv = d[j]; bj = j; }
        int bm = lane + (bj << 6);
        for (int off = 32; off > 0; off >>= 1) {
            float ov = __shfl_down(bv, off);
            int   om = __shfl_down(bm, off);
            if (ov > bv || (ov == bv && om < bm)) { bv = ov; bm = om; }
        }
        bm = __shfl(bm, 0);
        if (lane == 0) idxo[rg * K + it] = bm;
        if ((bm & 63) == lane) d[bm >> 6] = -FLT_MAX;
    }
}

// ---- V[b][n][o] = X·Wa^T, U[b][n][o] = X·(Wb-Wa)^T ; w is [O][2C] ----
__global__ __launch_bounds__(256) void k_uv(const float* __restrict__ X, const float* __restrict__ w,
                                            float* __restrict__ V, float* __restrict__ U,
                                            int Cp, int C, int O) {
    int n0 = blockIdx.x * 64, o0 = blockIdx.y * 64, b = blockIdx.z;
    __shared__ float Xs[64][33], Was[64][33], Wds[64][33];
    int tid = threadIdx.x, ti = tid & 15, tj = tid >> 4;
    float accv[4][4] = {}, accu[4][4] = {};
    const float* Xb = X + (((size_t)b) << 10) * Cp;
    int W2 = 2 * C;
    for (int c0 = 0; c0 < Cp; c0 += 32) {
        for (int e = tid; e < 2048; e += 256) {
            int row = e >> 5, cc = e & 31, c = c0 + cc;
            Xs[row][cc] = (c < Cp) ? Xb[(size_t)(n0 + row) * Cp + c] : 0.f;
            float wa = 0.f, wd = 0.f;
            if (c < C) {
                float a_ = w[(size_t)(o0 + row) * W2 + c];
                float b_ = w[(size_t)(o0 + row) * W2 + C + c];
                wa = a_; wd = b_ - a_;
            }
            Was[row][cc] = wa; Wds[row][cc] = wd;
        }
        __syncthreads();
#pragma unroll 8
        for (int cc = 0; cc < 32; ++cc) {
            float xv[4], av[4], dv[4];
#pragma unroll
            for (int a = 0; a < 4; ++a) xv[a] = Xs[tj + 16 * a][cc];
#pragma unroll
            for (int q = 0; q < 4; ++q) { av[q] = Was[ti + 16 * q][cc]; dv[q] = Wds[ti + 16 * q][cc]; }
#pragma unroll
            for (int a = 0; a < 4; ++a)
#pragma unroll
                for (int q = 0; q < 4; ++q) { accv[a][q] += xv[a] * av[q]; accu[a][q] += xv[a] * dv[q]; }
        }
        __syncthreads();
    }
#pragma unroll
    for (int a = 0; a < 4; ++a) {
        int n = n0 + tj + 16 * a;
#pragma unroll
        for (int q = 0; q < 4; ++q) {
            int o = o0 + ti + 16 * q;
            size_t oi = ((size_t)((b << 10) + n)) * O + o;
            V[oi] = accv[a][q]; U[oi] = accu[a][q];
        }
    }
}

// ---- out[b][n][o] = max_k leaky(bn(V[m_k]+U[n])); writes f32 Xo, bf16 HB col-slice, xx ----
__global__ __launch_bounds__(256) void k_gmax(const float* __restrict__ V, const float* __restrict__ U,
                                              const int* __restrict__ idx,
                                              const float* __restrict__ gg, const float* __restrict__ bb,
                                              float* __restrict__ Xo, float* __restrict__ xx,
                                              unsigned short* __restrict__ HB, int coff, int O) {
    __shared__ float sxx[4];
    int tid = threadIdx.x;
    int Tn = 256 / O;
    int j = tid / O, o = tid - j * O;
    int pt = blockIdx.x * Tn + j;          // global point = b*1024+n
    int b = pt >> 10;
    float uv = U[(size_t)pt * O + o];
    float gv = gg[o], bv = bb[o];
    const int* ip = idx + (size_t)pt * 20;
    float mx = -FLT_MAX;
    for (int k = 0; k < 20; ++k) {
        int m = ip[k] & 1023;
        float vv = V[(size_t)((b << 10) + m) * O + o];
        float y = gv * ((vv + uv) * BNS_C) + bv;
        y = y > 0.f ? y : 0.2f * y;
        mx = fmaxf(mx, y);
    }
    Xo[(size_t)pt * O + o] = mx;
    HB[(size_t)pt * 512 + coff + o] = f2bf(mx);
    // per-point squared-norm for the next block's gram (O is a multiple of 64)
    float s = mx * mx;
#pragma unroll
    for (int off = 32; off; off >>= 1) s += __shfl_down(s, off);
    int wid = tid >> 6, lane = tid & 63;
    if (lane == 0) sxx[wid] = s;
    __syncthreads();
    if (o == 0) {
        int Wpp = O >> 6;
        float t = 0.f;
        for (int w = 0; w < Wpp; ++w) t += sxx[j * Wpp + w];
        xx[pt] = t;
    }
}

// ------- fused MFMA GEMM + BN/leaky + partial max/sum pool over a 256-row n-tile -------
// grid (batch, o-strip, n-tile): batch in blockIdx.x so all blocks of one batch share an
// XCD (round-robin by linear id) -> HB slice L2-resident. Partials to pp, reduced later.
__global__ __launch_bounds__(256) void k_final_mfma(const unsigned short* __restrict__ HB,
                                                    const float* __restrict__ w5,
                                                    const float* __restrict__ g5,
                                                    const float* __restrict__ b5,
                                                    float* __restrict__ pp) {
    int b = blockIdx.x;
    int nt = blockIdx.z;
    int wv = threadIdx.x >> 6, lane = threadIdx.x & 63;
    int r = lane & 15, q = lane >> 4;
    int o = blockIdx.y * 64 + wv * 16 + r;          // this lane's output column
    // B fragments: Bfr[s] = w5[o][32s + 8q + j], j=0..7 (B[k][n] layout: n=lane&15, k=8q+j)
    bf8 Bfr[16];
    const float* wrow = w5 + (size_t)o * 512 + q * 8;
#pragma unroll
    for (int s = 0; s < 16; ++s) {
        float4 f0 = *(const float4*)(wrow + s * 32);
        float4 f1 = *(const float4*)(wrow + s * 32 + 4);
        I4BF8 u_;
        u_.i.x = f2bf(f0.x) | ((unsigned)f2bf(f0.y) << 16);
        u_.i.y = f2bf(f0.z) | ((unsigned)f2bf(f0.w) << 16);
        u_.i.z = f2bf(f1.x) | ((unsigned)f2bf(f1.y) << 16);
        u_.i.w = f2bf(f1.z) | ((unsigned)f2bf(f1.w) << 16);
        Bfr[s] = u_.b;
    }
    float gb = g5[o] * BNS_C, bv = b5[o];
    const unsigned short* HBb = HB + ((((size_t)b) << 10) + (nt << 8)) * 512 + q * 8;
    float mx = -FLT_MAX, sm = 0.f;
    for (int g = 0; g < 4; ++g) {
        const unsigned short* a0 = HBb + (size_t)(g * 64 +  0 + r) * 512;
        const unsigned short* a1 = HBb + (size_t)(g * 64 + 16 + r) * 512;
        const unsigned short* a2 = HBb + (size_t)(g * 64 + 32 + r) * 512;
        const unsigned short* a3 = HBb + (size_t)(g * 64 + 48 + r) * 512;
        f4 C0 = {0.f, 0.f, 0.f, 0.f}, C1 = C0, C2 = C0, C3 = C0;
#pragma unroll
        for (int s = 0; s < 16; ++s) {
            I4BF8 A0, A1, A2, A3;
            A0.i = *(const int4*)(a0 + s * 32);
            A1.i = *(const int4*)(a1 + s * 32);
            A2.i = *(const int4*)(a2 + s * 32);
            A3.i = *(const int4*)(a3 + s * 32);
            C0 = __builtin_amdgcn_mfma_f32_16x16x32_bf16(A0.b, Bfr[s], C0, 0, 0, 0);
            C1 = __builtin_amdgcn_mfma_f32_16x16x32_bf16(A1.b, Bfr[s], C1, 0, 0, 0);
            C2 = __builtin_amdgcn_mfma_f32_16x16x32_bf16(A2.b, Bfr[s], C2, 0, 0, 0);
            C3 = __builtin_amdgcn_mfma_f32_16x16x32_bf16(A3.b, Bfr[s], C3, 0, 0, 0);
        }
#pragma unroll
        for (int e = 0; e < 4; ++e) {
            float y0 = gb * C0[e] + bv; y0 = y0 > 0.f ? y0 : 0.2f * y0; mx = fmaxf(mx, y0); sm += y0;
            float y1 = gb * C1[e] + bv; y1 = y1 > 0.f ? y1 : 0.2f * y1; mx = fmaxf(mx, y1); sm += y1;
            float y2 = gb * C2[e] + bv; y2 = y2 > 0.f ? y2 : 0.2f * y2; mx = fmaxf(mx, y2); sm += y2;
            float y3 = gb * C3[e] + bv; y3 = y3 > 0.f ? y3 : 0.2f * y3; mx = fmaxf(mx, y3); sm += y3;
        }
    }
    // combine the 4 q-groups (lanes +16,+32,+48 share the same o)
    mx = fmaxf(mx, __shfl_down(mx, 32)); sm += __shfl_down(sm, 32);
    mx = fmaxf(mx, __shfl_down(mx, 16)); sm += __shfl_down(sm, 16);
    if (q == 0) {
        float* pb = pp + (size_t)(nt * 16 + b) * 2048;
        pb[o] = mx;
        pb[1024 + o] = sm;
    }
}

// ------- stage-2: reduce 4 n-tile partials -> p[b][2048] -------
__global__ void k_pfinal(const float* __restrict__ pp, float* __restrict__ p) {
    int i = blockIdx.x * 256 + threadIdx.x;  // over 16*1024
    int b = i >> 10, o = i & 1023;
    float mx = -FLT_MAX, sm = 0.f;
    for (int nt = 0; nt < 4; ++nt) {
        const float* q = pp + (size_t)(nt * 16 + b) * 2048;
        mx = fmaxf(mx, q[o]); sm += q[1024 + o];
    }
    p[b * 2048 + o] = mx;
    p[b * 2048 + 1024 + o] = sm * (1.f / 1024.f);
}

// ---------------- FC: one wave per (r,o); coalesced lane-strided C loop ----------------
__global__ __launch_bounds__(256) void k_fc2(const float* __restrict__ in, const float* __restrict__ w,
                                             const float* __restrict__ gg, const float* __restrict__ bb,
                                             float* __restrict__ out,
                                             int R, int C, int O, int act) {
    int gw = blockIdx.x * 4 + (threadIdx.x >> 6);   // global wave id
    int lane = threadIdx.x & 63;
    if (gw >= R * O) return;
    int r = gw / O, o = gw - r * O;
    const float* ir = in + (size_t)r * C;
    const float* wr = w + (size_t)o * C;
    float s = 0.f;
    for (int c = lane; c < C; c += 64) s += ir[c] * wr[c];
#pragma unroll
    for (int off = 32; off; off >>= 1) s += __shfl_down(s, off);
    if (lane == 0) {
        float y = s;
        if (gg) y = gg[o] * (s * BNS_C) + bb[o];
        if (act == 1) y = y > 0.f ? y : 0.2f * y;
        else if (act == 2) y = 0.5f * y * (1.f + erff(y * 0.70710678118654752f));
        out[gw] = y;
    }
}

// ------- FC tail mega-kernel: z1 -> wl2/bn7/leaky -> wl21 -> wl22/bn8/gelu -> wl3 -> out -------
// single block; activations live in LDS; 16 consecutive threads share a weight row (broadcast).
__global__ __launch_bounds__(256) void k_fc_tail(const float* __restrict__ z1,
                                                 const float* __restrict__ wl2, const float* __restrict__ g7, const float* __restrict__ b7,
                                                 const float* __restrict__ wl21,
                                                 const float* __restrict__ wl22, const float* __restrict__ g8, const float* __restrict__ b8,
                                                 const float* __restrict__ wl3,
                                                 float* __restrict__ out) {
    __shared__ float L0[4096];   // z1  16x256
    __shared__ float L1[2048];   // z2  16x128
    __shared__ float L2[1024];   // zt  16x64
    __shared__ float L3[512];    // z3  16x32
    int tid = threadIdx.x;
    for (int i = tid; i < 4096; i += 256) L0[i] = z1[i];
    __syncthreads();
    // layer A: 16x128, C=256, bn7 + leaky
    for (int idx = tid; idx < 2048; idx += 256) {
        int o = idx >> 4, r = idx & 15;
        const float* wr = wl2 + (size_t)o * 256;
        const float* ir = L0 + r * 256;
        float s = 0.f;
        for (int c = 0; c < 256; ++c) s += ir[c] * wr[c];
        float y = g7[o] * (s * BNS_C) + b7[o];
        L1[r * 128 + o] = y > 0.f ? y : 0.2f * y;
    }
    __syncthreads();
    // layer B: 16x64, C=128, linear
    for (int idx = tid; idx < 1024; idx += 256) {
        int o = idx >> 4, r = idx & 15;
        const float* wr = wl21 + (size_t)o * 128;
        const float* ir = L1 + r * 128;
        float s = 0.f;
        for (int c = 0; c < 128; ++c) s += ir[c] * wr[c];
        L2[r * 64 + o] = s;
    }
    __syncthreads();
    // layer C: 16x32, C=64, bn8 + exact gelu
    for (int idx = tid; idx < 512; idx += 256) {
        int o = idx >> 4, r = idx & 15;
        const float* wr = wl22 + (size_t)o * 64;
        const float* ir = L2 + r * 64;
        float s = 0.f;
        for (int c = 0; c < 64; ++c) s += ir[c] * wr[c];
        float y = g8[o] * (s * BNS_C) + b8[o];
        L3[r * 32 + o] = 0.5f * y * (1.f + erff(y * 0.70710678118654752f));
    }
    __syncthreads();
    // layer D: 16x90, C=32, linear -> d_out
    for (int idx = tid; idx < 1440; idx += 256) {
        int o = idx / 16, r = idx & 15;
        const float* wr = wl3 + (size_t)o * 32;
        const float* ir = L3 + r * 32;
        float s = 0.f;
        for (int c = 0; c < 32; ++c) s += ir[c] * wr[c];
        out[r * 90 + o] = s;
    }
}

extern "C" void kernel_launch(void* const* d_in, const int* in_sizes, int n_in,
                              void* d_out, int out_size, void* d_ws, size_t ws_size,
                              hipStream_t stream) {
    typedef const float* fp;
    fp x  = (fp)d_in[0];
    fp w1 = (fp)d_in[2],  g1 = (fp)d_in[3],  b1 = (fp)d_in[4];
    fp w2 = (fp)d_in[5],  g2 = (fp)d_in[6],  b2 = (fp)d_in[7];
    fp w3 = (fp)d_in[8],  g3 = (fp)d_in[9],  b3 = (fp)d_in[10];
    fp w4 = (fp)d_in[11], g4 = (fp)d_in[12], b4 = (fp)d_in[13];
    fp w5 = (fp)d_in[14], g5 = (fp)d_in[15], b5 = (fp)d_in[16];
    fp wl1 = (fp)d_in[17], g6 = (fp)d_in[18], b6 = (fp)d_in[19];
    fp wl2 = (fp)d_in[20], g7 = (fp)d_in[21], b7 = (fp)d_in[22];
    fp wl21 = (fp)d_in[23], wl22 = (fp)d_in[24];
    fp g8 = (fp)d_in[25], b8 = (fp)d_in[26], wl3 = (fp)d_in[27];

    char* ws = (char*)d_ws;
    size_t off = 0;
    auto alloc = [&](size_t floats) { float* p_ = (float*)(ws + off); off += floats * 4; off = (off + 255) & ~(size_t)255; return p_; };
    float* X0  = alloc(131072);       // 16*1024*8
    float* X1  = alloc(1048576);      // [b][n][64]
    float* X2  = alloc(1048576);
    float* X3  = alloc(2097152);      // [b][n][128]
    float* X4  = alloc(4194304);      // [b][n][256]
    float* xx  = alloc(16384);
    int*   nbr = (int*)alloc(327680); // 16*1024*20
    unsigned short* HB = (unsigned short*)alloc(4194304);  // bf16 [16*1024][512] concat feats
    float* pp  = alloc(131072);       // 4 n-tile partials x 16 b x 2048
    float* p   = alloc(32768);
    float* z1  = alloc(4096);
    // pool: union of D | V+U
    size_t poolAvail = (ws_size > off) ? (ws_size - off) / 4 : 0;
    int fullD = poolAvail >= 16777216;                 // 64 MB full distance tensor
    float* pool = alloc(fullD ? 16777216 : 8388608);

    float* D = pool;
    float* V = pool;
    float* U = pool + 4194304;

    k_xin_t<<<64, 256, 0, stream>>>(x, X0, xx);

    struct Blk { const float* Xin; int Cp, C, O, coff; const float *w, *g, *b; float* Xout; };
    Blk blks[4] = {
        {X0, 8,   6,   64,  0,   w1, g1, b1, X1},
        {X1, 64,  64,  64,  64,  w2, g2, b2, X2},
        {X2, 64,  64,  128, 128, w3, g3, b3, X3},
        {X3, 128, 128, 256, 256, w4, g4, b4, X4},
    };
    for (int i = 0; i < 4; ++i) {
        const Blk& B_ = blks[i];
        if (fullD) {
            k_gram2<<<dim3(16, 16, 16), 256, 0, stream>>>(B_.Xin, xx, D, B_.Cp, 0);
            k_topk<<<4096, 256, 0, stream>>>(D, nbr, 0);
        } else {
            for (int b0 = 0; b0 < 16; b0 += 8) {
                k_gram2<<<dim3(16, 16, 8), 256, 0, stream>>>(B_.Xin, xx, D, B_.Cp, b0);
                k_topk<<<2048, 256, 0, stream>>>(D, nbr, b0);
            }
        }
        k_uv<<<dim3(16, B_.O / 64, 16), 256, 0, stream>>>(B_.Xin, B_.w, V, U, B_.Cp, B_.C, B_.O);
        int Tn = 256 / B_.O;
        k_gmax<<<16384 / Tn, 256, 0, stream>>>(V, U, nbr, B_.g, B_.b, B_.Xout, xx, HB, B_.coff, B_.O);
    }

    k_final_mfma<<<dim3(16, 16, 4), 256, 0, stream>>>(HB, w5, g5, b5, pp);
    k_pfinal<<<64, 256, 0, stream>>>(pp, p);

    k_fc2<<<(16 * 256 + 3) / 4, 256, 0, stream>>>(p, wl1, g6, b6, z1, 16, 2048, 256, 1);
    k_fc_tail<<<1, 256, 0, stream>>>(z1, wl2, g7, b7, wl21, wl22, g8, b8, wl3, (float*)d_out);
}

// Round 11
// 992.971 us; speedup vs baseline: 1.0427x; 1.0427x over previous
//
#include <hip/hip_runtime.h>
#include <math.h>
#include <float.h>

#define BNS_C 0.9999950000374996f /* 1/sqrt(1+1e-5) */

typedef __bf16 bf8 __attribute__((ext_vector_type(8)));
typedef float f4 __attribute__((ext_vector_type(4)));
union I4BF8 { int4 i; bf8 b; };

static __device__ __forceinline__ unsigned short f2bf(float f) {
    unsigned u = __float_as_uint(f);
    u += 0x7fff + ((u >> 16) & 1);          // round-to-nearest-even
    return (unsigned short)(u >> 16);
}

// ------- x[b][6][1024] -> X0[b][n][8] (zero-padded) + xx norms -------
__global__ void k_xin_t(const float* __restrict__ x, float* __restrict__ X0, float* __restrict__ xx) {
    int i = blockIdx.x * 256 + threadIdx.x;   // over 16384 points
    int b = i >> 10, n = i & 1023;
    const float* xb = x + (((size_t)b * 6) << 10) + n;
    float4* o4 = (float4*)(X0 + ((size_t)i << 3));
    float v0 = xb[0], v1 = xb[1 << 10], v2 = xb[2 << 10];
    float v3 = xb[3 << 10], v4 = xb[4 << 10], v5 = xb[5 << 10];
    o4[0] = make_float4(v0, v1, v2, v3);
    o4[1] = make_float4(v4, v5, 0.f, 0.f);
    xx[i] = v0*v0 + v1*v1 + v2*v2 + v3*v3 + v4*v4 + v5*v5;
}

// ---- D[z][n][m] = 2*X[n]·X[m] - xx[n] - xx[m], X point-major; z over chunk ----
__global__ __launch_bounds__(256) void k_gram2(const float* __restrict__ X, const float* __restrict__ xx,
                                               float* __restrict__ D, int Cp, int b0) {
    int z = blockIdx.z, b = b0 + z;
    int n0 = blockIdx.y * 64, m0 = blockIdx.x * 64;
    __shared__ float As[64][33], Bs[64][33];
    int tid = threadIdx.x;
    int ti = tid & 15, tj = tid >> 4;
    float acc[4][4] = {};
    const float* Xb = X + (((size_t)b) << 10) * Cp;
    for (int c0 = 0; c0 < Cp; c0 += 32) {
        for (int e = tid; e < 2048; e += 256) {
            int row = e >> 5, cc = e & 31, c = c0 + cc;
            float a = 0.f, bb = 0.f;
            if (c < Cp) {
                a  = Xb[(size_t)(n0 + row) * Cp + c];
                bb = Xb[(size_t)(m0 + row) * Cp + c];
            }
            As[row][cc] = a; Bs[row][cc] = bb;
        }
        __syncthreads();
#pragma unroll 8
        for (int cc = 0; cc < 32; ++cc) {
            float xv[4], yv[4];
#pragma unroll
            for (int a = 0; a < 4; ++a) xv[a] = As[tj + 16 * a][cc];
#pragma unroll
            for (int q = 0; q < 4; ++q) yv[q] = Bs[ti + 16 * q][cc];
#pragma unroll
            for (int a = 0; a < 4; ++a)
#pragma unroll
                for (int q = 0; q < 4; ++q) acc[a][q] += xv[a] * yv[q];
        }
        __syncthreads();
    }
#pragma unroll
    for (int a = 0; a < 4; ++a) {
        int n = n0 + tj + 16 * a;
        float xn = xx[(b << 10) + n];
#pragma unroll
        for (int q = 0; q < 4; ++q) {
            int m = m0 + ti + 16 * q;
            D[((size_t)((z << 10) + n) << 10) + m] = 2.f * acc[a][q] - xn - xx[(b << 10) + m];
        }
    }
}

// ---------------- top-20 per row, one wave per row (rows chunk-local) ----------------
__global__ __launch_bounds__(256) void k_topk(const float* __restrict__ D, int* __restrict__ idxo, int b0) {
    const int K = 20;
    int lane = threadIdx.x & 63;
    int rl = blockIdx.x * 4 + (threadIdx.x >> 6);
    const float* row = D + ((size_t)rl << 10);
    float d[16];
#pragma unroll
    for (int j = 0; j < 16; ++j) d[j] = row[lane + 64 * j];
    int rg = (b0 << 10) + rl;
    for (int it = 0; it < K; ++it) {
        float bv = d[0]; int bj = 0;
#pragma unroll
        for (int j = 1; j < 16; ++j) if (d[j] > bv) { bv = d[j]; bj = j; }
        int bm = lane + (bj << 6);
        for (int off = 32; off > 0; off >>= 1) {
            float ov = __shfl_down(bv, off);
            int   om = __shfl_down(bm, off);
            if (ov > bv || (ov == bv && om < bm)) { bv = ov; bm = om; }
        }
        bm = __shfl(bm, 0);
        if (lane == 0) idxo[rg * K + it] = bm;
        if ((bm & 63) == lane) d[bm >> 6] = -FLT_MAX;
    }
}

// ---- V[b][n][o] = X·Wa^T, U[b][n][o] = X·(Wb-Wa)^T ; w is [O][2C] ----
__global__ __launch_bounds__(256) void k_uv(const float* __restrict__ X, const float* __restrict__ w,
                                            float* __restrict__ V, float* __restrict__ U,
                                            int Cp, int C, int O) {
    int n0 = blockIdx.x * 64, o0 = blockIdx.y * 64, b = blockIdx.z;
    __shared__ float Xs[64][33], Was[64][33], Wds[64][33];
    int tid = threadIdx.x, ti = tid & 15, tj = tid >> 4;
    float accv[4][4] = {}, accu[4][4] = {};
    const float* Xb = X + (((size_t)b) << 10) * Cp;
    int W2 = 2 * C;
    for (int c0 = 0; c0 < Cp; c0 += 32) {
        for (int e = tid; e < 2048; e += 256) {
            int row = e >> 5, cc = e & 31, c = c0 + cc;
            Xs[row][cc] = (c < Cp) ? Xb[(size_t)(n0 + row) * Cp + c] : 0.f;
            float wa = 0.f, wd = 0.f;
            if (c < C) {
                float a_ = w[(size_t)(o0 + row) * W2 + c];
                float b_ = w[(size_t)(o0 + row) * W2 + C + c];
                wa = a_; wd = b_ - a_;
            }
            Was[row][cc] = wa; Wds[row][cc] = wd;
        }
        __syncthreads();
#pragma unroll 8
        for (int cc = 0; cc < 32; ++cc) {
            float xv[4], av[4], dv[4];
#pragma unroll
            for (int a = 0; a < 4; ++a) xv[a] = Xs[tj + 16 * a][cc];
#pragma unroll
            for (int q = 0; q < 4; ++q) { av[q] = Was[ti + 16 * q][cc]; dv[q] = Wds[ti + 16 * q][cc]; }
#pragma unroll
            for (int a = 0; a < 4; ++a)
#pragma unroll
                for (int q = 0; q < 4; ++q) { accv[a][q] += xv[a] * av[q]; accu[a][q] += xv[a] * dv[q]; }
        }
        __syncthreads();
    }
#pragma unroll
    for (int a = 0; a < 4; ++a) {
        int n = n0 + tj + 16 * a;
#pragma unroll
        for (int q = 0; q < 4; ++q) {
            int o = o0 + ti + 16 * q;
            size_t oi = ((size_t)((b << 10) + n)) * O + o;
            V[oi] = accv[a][q]; U[oi] = accu[a][q];
        }
    }
}

// ---- out[b][n][o] = max_k leaky(bn(V[m_k]+U[n])); writes f32 Xo, k-sliced bf16 HB, xx ----
// HB2 layout: element (b, n, c) at ((b*16 + (c>>5))*1024 + n)*32 + (c&31)  [s-slab k-major]
__global__ __launch_bounds__(256) void k_gmax(const float* __restrict__ V, const float* __restrict__ U,
                                              const int* __restrict__ idx,
                                              const float* __restrict__ gg, const float* __restrict__ bb,
                                              float* __restrict__ Xo, float* __restrict__ xx,
                                              unsigned short* __restrict__ HB, int coff, int O) {
    __shared__ float sxx[4];
    int tid = threadIdx.x;
    int Tn = 256 / O;
    int j = tid / O, o = tid - j * O;
    int pt = blockIdx.x * Tn + j;          // global point = b*1024+n
    int b = pt >> 10, n = pt & 1023;
    float uv = U[(size_t)pt * O + o];
    float gv = gg[o], bv = bb[o];
    const int* ip = idx + (size_t)pt * 20;
    float mx = -FLT_MAX;
    for (int k = 0; k < 20; ++k) {
        int m = ip[k] & 1023;
        float vv = V[(size_t)((b << 10) + m) * O + o];
        float y = gv * ((vv + uv) * BNS_C) + bv;
        y = y > 0.f ? y : 0.2f * y;
        mx = fmaxf(mx, y);
    }
    Xo[(size_t)pt * O + o] = mx;
    int c = coff + o;
    HB[(((size_t)(b * 16 + (c >> 5)) << 10) + n) * 32 + (c & 31)] = f2bf(mx);
    // per-point squared-norm for the next block's gram (O is a multiple of 64)
    float s = mx * mx;
#pragma unroll
    for (int off = 32; off; off >>= 1) s += __shfl_down(s, off);
    int wid = tid >> 6, lane = tid & 63;
    if (lane == 0) sxx[wid] = s;
    __syncthreads();
    if (o == 0) {
        int Wpp = O >> 6;
        float t = 0.f;
        for (int w = 0; w < Wpp; ++w) t += sxx[j * Wpp + w];
        xx[pt] = t;
    }
}

// ------- fused MFMA GEMM + BN/leaky + partial max/sum pool over a 256-row n-tile -------
// A-loads from k-sliced HB2: each chain load spans r*64B + q*16B = contiguous 1 KB/wave.
__global__ __launch_bounds__(256) void k_final_mfma(const unsigned short* __restrict__ HB,
                                                    const float* __restrict__ w5,
                                                    const float* __restrict__ g5,
                                                    const float* __restrict__ b5,
                                                    float* __restrict__ pp) {
    int b = blockIdx.x;
    int nt = blockIdx.z;
    int wv = threadIdx.x >> 6, lane = threadIdx.x & 63;
    int r = lane & 15, q = lane >> 4;
    int o = blockIdx.y * 64 + wv * 16 + r;          // this lane's output column
    // B fragments: Bfr[s] = w5[o][32s + 8q + j], j=0..7
    bf8 Bfr[16];
    const float* wrow = w5 + (size_t)o * 512 + q * 8;
#pragma unroll
    for (int s = 0; s < 16; ++s) {
        float4 f0 = *(const float4*)(wrow + s * 32);
        float4 f1 = *(const float4*)(wrow + s * 32 + 4);
        I4BF8 u_;
        u_.i.x = f2bf(f0.x) | ((unsigned)f2bf(f0.y) << 16);
        u_.i.y = f2bf(f0.z) | ((unsigned)f2bf(f0.w) << 16);
        u_.i.z = f2bf(f1.x) | ((unsigned)f2bf(f1.y) << 16);
        u_.i.w = f2bf(f1.z) | ((unsigned)f2bf(f1.w) << 16);
        Bfr[s] = u_.b;
    }
    float gb = g5[o] * BNS_C, bv = b5[o];
    float mx = -FLT_MAX, sm = 0.f;
    for (int g = 0; g < 4; ++g) {
        int row0 = (nt << 8) + (g << 6);
        f4 C0 = {0.f, 0.f, 0.f, 0.f}, C1 = C0, C2 = C0, C3 = C0;
#pragma unroll
        for (int s = 0; s < 16; ++s) {
            const unsigned short* slab = HB + (((size_t)(b * 16 + s) << 10) + row0) * 32 + q * 8;
            I4BF8 A0, A1, A2, A3;
            A0.i = *(const int4*)(slab + (size_t)( 0 + r) * 32);
            A1.i = *(const int4*)(slab + (size_t)(16 + r) * 32);
            A2.i = *(const int4*)(slab + (size_t)(32 + r) * 32);
            A3.i = *(const int4*)(slab + (size_t)(48 + r) * 32);
            C0 = __builtin_amdgcn_mfma_f32_16x16x32_bf16(A0.b, Bfr[s], C0, 0, 0, 0);
            C1 = __builtin_amdgcn_mfma_f32_16x16x32_bf16(A1.b, Bfr[s], C1, 0, 0, 0);
            C2 = __builtin_amdgcn_mfma_f32_16x16x32_bf16(A2.b, Bfr[s], C2, 0, 0, 0);
            C3 = __builtin_amdgcn_mfma_f32_16x16x32_bf16(A3.b, Bfr[s], C3, 0, 0, 0);
        }
#pragma unroll
        for (int e = 0; e < 4; ++e) {
            float y0 = gb * C0[e] + bv; y0 = y0 > 0.f ? y0 : 0.2f * y0; mx = fmaxf(mx, y0); sm += y0;
            float y1 = gb * C1[e] + bv; y1 = y1 > 0.f ? y1 : 0.2f * y1; mx = fmaxf(mx, y1); sm += y1;
            float y2 = gb * C2[e] + bv; y2 = y2 > 0.f ? y2 : 0.2f * y2; mx = fmaxf(mx, y2); sm += y2;
            float y3 = gb * C3[e] + bv; y3 = y3 > 0.f ? y3 : 0.2f * y3; mx = fmaxf(mx, y3); sm += y3;
        }
    }
    // combine the 4 q-groups (lanes +16,+32,+48 share the same o)
    mx = fmaxf(mx, __shfl_down(mx, 32)); sm += __shfl_down(sm, 32);
    mx = fmaxf(mx, __shfl_down(mx, 16)); sm += __shfl_down(sm, 16);
    if (q == 0) {
        float* pb = pp + (size_t)(nt * 16 + b) * 2048;
        pb[o] = mx;
        pb[1024 + o] = sm;
    }
}

// ---- wl1 FC fused with the n-tile partial reduction: reads pp directly ----
__global__ __launch_bounds__(256) void k_fc2p(const float* __restrict__ pp, const float* __restrict__ w,
                                              const float* __restrict__ gg, const float* __restrict__ bb,
                                              float* __restrict__ out, int O) {
    int gw = blockIdx.x * 4 + (threadIdx.x >> 6);   // global wave id over 16*O
    int lane = threadIdx.x & 63;
    int r = gw / O, o = gw - r * O;
    const float* wr = w + (size_t)o * 2048;
    float s = 0.f;
    for (int c = lane; c < 2048; c += 64) {
        const float* q0 = pp + (size_t)r * 2048 + c;
        float v;
        if (c < 1024) {
            v = fmaxf(fmaxf(q0[0], q0[16 * 2048]), fmaxf(q0[32 * 2048], q0[48 * 2048]));
        } else {
            v = (q0[0] + q0[16 * 2048] + q0[32 * 2048] + q0[48 * 2048]) * (1.f / 1024.f);
        }
        s += v * wr[c];
    }
#pragma unroll
    for (int off = 32; off; off >>= 1) s += __shfl_down(s, off);
    if (lane == 0) {
        float y = gg[o] * (s * BNS_C) + bb[o];
        out[gw] = y > 0.f ? y : 0.2f * y;
    }
}

// ------- FC tail mega-kernel: z1 -> wl2/bn7/leaky -> wl21 -> wl22/bn8/gelu -> wl3 -> out -------
// lanes vary o, share r => activation reads are LDS broadcasts (no bank conflicts).
__global__ __launch_bounds__(256) void k_fc_tail(const float* __restrict__ z1,
                                                 const float* __restrict__ wl2, const float* __restrict__ g7, const float* __restrict__ b7,
                                                 const float* __restrict__ wl21,
                                                 const float* __restrict__ wl22, const float* __restrict__ g8, const float* __restrict__ b8,
                                                 const float* __restrict__ wl3,
                                                 float* __restrict__ out) {
    __shared__ float L0[4096];   // z1  16x256
    __shared__ float L1[2048];   // z2  16x128
    __shared__ float L2[1024];   // zt  16x64
    __shared__ float L3[512];    // z3  16x32
    int tid = threadIdx.x;
    for (int i = tid; i < 4096; i += 256) L0[i] = z1[i];
    __syncthreads();
    // layer A: 16x128, C=256, bn7 + leaky
    for (int idx = tid; idx < 2048; idx += 256) {
        int r = idx >> 7, o = idx & 127;
        const float* wr = wl2 + (size_t)o * 256;
        const float* ir = L0 + r * 256;
        float s = 0.f;
        for (int c = 0; c < 256; ++c) s += ir[c] * wr[c];
        float y = g7[o] * (s * BNS_C) + b7[o];
        L1[r * 128 + o] = y > 0.f ? y : 0.2f * y;
    }
    __syncthreads();
    // layer B: 16x64, C=128, linear
    for (int idx = tid; idx < 1024; idx += 256) {
        int r = idx >> 6, o = idx & 63;
        const float* wr = wl21 + (size_t)o * 128;
        const float* ir = L1 + r * 128;
        float s = 0.f;
        for (int c = 0; c < 128; ++c) s += ir[c] * wr[c];
        L2[r * 64 + o] = s;
    }
    __syncthreads();
    // layer C: 16x32, C=64, bn8 + exact gelu
    for (int idx = tid; idx < 512; idx += 256) {
        int r = idx >> 5, o = idx & 31;
        const float* wr = wl22 + (size_t)o * 64;
        const float* ir = L2 + r * 64;
        float s = 0.f;
        for (int c = 0; c < 64; ++c) s += ir[c] * wr[c];
        float y = g8[o] * (s * BNS_C) + b8[o];
        L3[r * 32 + o] = 0.5f * y * (1.f + erff(y * 0.70710678118654752f));
    }
    __syncthreads();
    // layer D: 16x90, C=32, linear -> d_out
    for (int idx = tid; idx < 1440; idx += 256) {
        int r = idx / 90, o = idx - r * 90;
        const float* wr = wl3 + (size_t)o * 32;
        const float* ir = L3 + r * 32;
        float s = 0.f;
        for (int c = 0; c < 32; ++c) s += ir[c] * wr[c];
        out[r * 90 + o] = s;
    }
}

extern "C" void kernel_launch(void* const* d_in, const int* in_sizes, int n_in,
                              void* d_out, int out_size, void* d_ws, size_t ws_size,
                              hipStream_t stream) {
    typedef const float* fp;
    fp x  = (fp)d_in[0];
    fp w1 = (fp)d_in[2],  g1 = (fp)d_in[3],  b1 = (fp)d_in[4];
    fp w2 = (fp)d_in[5],  g2 = (fp)d_in[6],  b2 = (fp)d_in[7];
    fp w3 = (fp)d_in[8],  g3 = (fp)d_in[9],  b3 = (fp)d_in[10];
    fp w4 = (fp)d_in[11], g4 = (fp)d_in[12], b4 = (fp)d_in[13];
    fp w5 = (fp)d_in[14], g5 = (fp)d_in[15], b5 = (fp)d_in[16];
    fp wl1 = (fp)d_in[17], g6 = (fp)d_in[18], b6 = (fp)d_in[19];
    fp wl2 = (fp)d_in[20], g7 = (fp)d_in[21], b7 = (fp)d_in[22];
    fp wl21 = (fp)d_in[23], wl22 = (fp)d_in[24];
    fp g8 = (fp)d_in[25], b8 = (fp)d_in[26], wl3 = (fp)d_in[27];

    char* ws = (char*)d_ws;
    size_t off = 0;
    auto alloc = [&](size_t floats) { float* p_ = (float*)(ws + off); off += floats * 4; off = (off + 255) & ~(size_t)255; return p_; };
    float* X0  = alloc(131072);       // 16*1024*8
    float* X1  = alloc(1048576);      // [b][n][64]
    float* X2  = alloc(1048576);
    float* X3  = alloc(2097152);      // [b][n][128]
    float* X4  = alloc(4194304);      // [b][n][256]
    float* xx  = alloc(16384);
    int*   nbr = (int*)alloc(327680); // 16*1024*20
    unsigned short* HB = (unsigned short*)alloc(4194304);  // bf16 k-sliced [b][s][n][32]
    float* pp  = alloc(131072);       // 4 n-tile partials x 16 b x 2048
    float* z1  = alloc(4096);
    // pool: union of D | V+U
    size_t poolAvail = (ws_size > off) ? (ws_size - off) / 4 : 0;
    int fullD = poolAvail >= 16777216;                 // 64 MB full distance tensor
    float* pool = alloc(fullD ? 16777216 : 8388608);

    float* D = pool;
    float* V = pool;
    float* U = pool + 4194304;

    k_xin_t<<<64, 256, 0, stream>>>(x, X0, xx);

    struct Blk { const float* Xin; int Cp, C, O, coff; const float *w, *g, *b; float* Xout; };
    Blk blks[4] = {
        {X0, 8,   6,   64,  0,   w1, g1, b1, X1},
        {X1, 64,  64,  64,  64,  w2, g2, b2, X2},
        {X2, 64,  64,  128, 128, w3, g3, b3, X3},
        {X3, 128, 128, 256, 256, w4, g4, b4, X4},
    };
    for (int i = 0; i < 4; ++i) {
        const Blk& B_ = blks[i];
        if (fullD) {
            k_gram2<<<dim3(16, 16, 16), 256, 0, stream>>>(B_.Xin, xx, D, B_.Cp, 0);
            k_topk<<<4096, 256, 0, stream>>>(D, nbr, 0);
        } else {
            for (int b0 = 0; b0 < 16; b0 += 8) {
                k_gram2<<<dim3(16, 16, 8), 256, 0, stream>>>(B_.Xin, xx, D, B_.Cp, b0);
                k_topk<<<2048, 256, 0, stream>>>(D, nbr, b0);
            }
        }
        k_uv<<<dim3(16, B_.O / 64, 16), 256, 0, stream>>>(B_.Xin, B_.w, V, U, B_.Cp, B_.C, B_.O);
        int Tn = 256 / B_.O;
        k_gmax<<<16384 / Tn, 256, 0, stream>>>(V, U, nbr, B_.g, B_.b, B_.Xout, xx, HB, B_.coff, B_.O);
    }

    k_final_mfma<<<dim3(16, 16, 4), 256, 0, stream>>>(HB, w5, g5, b5, pp);

    k_fc2p<<<(16 * 256) / 4, 256, 0, stream>>>(pp, wl1, g6, b6, z1, 256);
    k_fc_tail<<<1, 256, 0, stream>>>(z1, wl2, g7, b7, wl21, wl22, g8, b8, wl3, (float*)d_out);
}